// Round 1
// baseline (359.319 us; speedup 1.0000x reference)
//
#include <hip/hip_runtime.h>
#include <cstdint>

// Problem constants (fixed by reference: B=4, S=2048)
#define TOK  8192   // B*S
#define DEMB 1024   // N_EMBD
#define HID  4096   // HIDDEN
#define ADP  256    // ADAPT
#define NEXP 8
#define KAUG 4352   // HID + ADP (K-augmented out-proj)

typedef __bf16 bf16x8 __attribute__((ext_vector_type(8)));
typedef float  f32x4  __attribute__((ext_vector_type(4)));

__device__ __forceinline__ unsigned short f2bf(float f) {
  // round-to-nearest-even fp32 -> bf16 (matches numpy/jax cast for normal values)
  unsigned int u = __float_as_uint(f);
  u += 0x7fffu + ((u >> 16) & 1u);
  return (unsigned short)(u >> 16);
}
__device__ __forceinline__ float bf2f(unsigned short b) {
  return __uint_as_float(((unsigned int)b) << 16);
}

// ---------------------------------------------------------------------------
// fp32 -> bf16 conversion for x and weights + routing + Wproj transpose, one
// kernel (block-range dispatch). Blocks:
//   [0,8960)    : 2048-elem conversion chunks (x, wup, wout->strided, wadapt, wexp)
//   [8960,8992) : routing (last active expert, -1 if none)
//   [8992,9248) : transpose-convert W_proj [4096,256] fp32 -> wpT [256,4096] bf16
// ---------------------------------------------------------------------------
__global__ __launch_bounds__(256) void convert_all(
    const float* __restrict__ x, const float* __restrict__ wup,
    const float* __restrict__ wout, const float* __restrict__ wadapt,
    const float* __restrict__ wexp, const float* __restrict__ ew,
    const float* __restrict__ wp,
    unsigned short* __restrict__ xb, unsigned short* __restrict__ wub,
    unsigned short* __restrict__ wob, unsigned short* __restrict__ wab,
    unsigned short* __restrict__ web, int* __restrict__ route,
    unsigned short* __restrict__ wpT) {
  __shared__ float tile[64][65];  // only used by transpose blocks
  int b = blockIdx.x;
  if (b >= 8992) {  // Wproj transpose: 64x64 LDS tiles, pad 65 (2-way = free)
    int wli = b - 8992;
    const int h0 = (wli & 63) * 64;  // over 4096
    const int a0 = (wli >> 6) * 64;  // over 256
    const int t = threadIdx.x;
    const int r = t >> 4;            // 0..15
    const int c = (t & 15) * 4;      // 0..60
#pragma unroll
    for (int p = 0; p < 4; ++p) {
      int row = p * 16 + r;
      float4 v = *(const float4*)(wp + (size_t)(h0 + row) * ADP + a0 + c);
      tile[c + 0][row] = v.x;
      tile[c + 1][row] = v.y;
      tile[c + 2][row] = v.z;
      tile[c + 3][row] = v.w;
    }
    __syncthreads();
#pragma unroll
    for (int q = 0; q < 2; ++q) {
      int idx = q * 256 + t;
      int al = idx >> 3;             // a local 0..63
      int hg = (idx & 7) * 8;        // h local 0,8,..,56
      unsigned int w0 = (unsigned int)f2bf(tile[al][hg + 0]) |
                        ((unsigned int)f2bf(tile[al][hg + 1]) << 16);
      unsigned int w1 = (unsigned int)f2bf(tile[al][hg + 2]) |
                        ((unsigned int)f2bf(tile[al][hg + 3]) << 16);
      unsigned int w2 = (unsigned int)f2bf(tile[al][hg + 4]) |
                        ((unsigned int)f2bf(tile[al][hg + 5]) << 16);
      unsigned int w3 = (unsigned int)f2bf(tile[al][hg + 6]) |
                        ((unsigned int)f2bf(tile[al][hg + 7]) << 16);
      *(uint4*)(wpT + (size_t)(a0 + al) * HID + h0 + hg) =
          make_uint4(w0, w1, w2, w3);
    }
    return;
  }
  if (b >= 8960) {  // routing
    int t = (b - 8960) * 256 + threadIdx.x;
    const float* p = ew + (size_t)t * NEXP;
    int r = -1;
#pragma unroll
    for (int e = 0; e < NEXP; ++e)
      if (p[e] > 0.f) r = e;
    route[t] = r;
    return;
  }
  const float* src; unsigned short* dst; int lb; bool strided = false;
  if      (b < 4096) { src = x;      dst = xb;  lb = b; }
  else if (b < 6144) { src = wup;    dst = wub; lb = b - 4096; }
  else if (b < 8192) { src = wout;   dst = wob; lb = b - 6144; strided = true; }
  else if (b < 8704) { src = wadapt; dst = wab; lb = b - 8192; }
  else               { src = wexp;   dst = web; lb = b - 8704; }
  size_t base = (size_t)lb * 2048;
#pragma unroll
  for (int h = 0; h < 2; ++h) {
    size_t off = base + (size_t)h * 1024 + (size_t)threadIdx.x * 4;
    float4 v = *(const float4*)(src + off);
    ushort4 o;
    o.x = f2bf(v.x); o.y = f2bf(v.y); o.z = f2bf(v.z); o.w = f2bf(v.w);
    size_t doff = strided ? (off >> 12) * KAUG + (off & 4095) : off;
    *(ushort4*)(dst + doff) = o;
  }
}

// XCD-aware remap: raw round-robin puts one N-strip per XCD and streams all
// of A through every XCD. Remap gives each XCD a contiguous band of gy/8
// row-tiles with all col-tiles co-resident (requires (gx*gy) % 8 == 0).
__device__ __forceinline__ void remap_xcd(int li, int gx, int gy,
                                          int& bx, int& by) {
  int xcd = li & 7;
  int slot = li >> 3;
  bx = slot % gx;
  by = xcd * (gy >> 3) + slot / gx;
}

// ===========================================================================
// 8-phase 256-wide GEMM (T2+T3+T4+T5): BM=128, BN=256, BK=64, 8 waves (2Mx4N),
// per-wave 64x64 output (acc[4][4] 16x16x32 bf16 MFMA). LDS 96 KiB:
// double-buffered A[128x64] + B[256x64], staged via global_load_lds width-16
// with the m97 XOR source-swizzle (bank-conflict-free reads, measured 0).
//
// Per K-tile: 4 phases, each {4x ds_read_b128 | stage issue -> s_barrier ->
// lgkmcnt(0) -> sched_barrier -> setprio(1) -> 8 MFMA -> setprio(0)}.
// Counted vmcnt(4) ONLY at ends of phases C and D (never 0 in main loop):
// prefetch depth 3-4 phases (~1000cy) covers HBM latency.
//
// Staging/readiness schedule (issue -> consume, per-thread 2 loads each):
//   D(t-1): A[t+1], Bh[t+1][0]   A(t): Bh[t+1][1]
//   read af[t+1,kk0] at D(t)   [vmcnt(4) end C(t) guarantees A[t+1]]
//   read bfr[t+1,kk0] at A(t+1)[vmcnt(4) end D(t) guarantees Bh[t+1][0,1]]
// Region-reuse safety: every stage targets a region whose last ds_read
// completed >=1 barrier earlier (reads pinned by per-phase lgkmcnt(0)).
// EPI: 0 = silu->bf16, 1 = fp32 store, 3 = expert-select fp32 store.
// ===========================================================================
__device__ __forceinline__ void read_frag4(const unsigned short* base, int lane,
                                           int rowoff, int kk, bf16x8* dst) {
#pragma unroll
  for (int i = 0; i < 4; ++i) {
    int rr = rowoff + i * 16 + (lane & 15);
    int sw = ((kk >> 3) + (lane >> 4)) ^ (lane & 7);  // rr&7 == lane&7
    dst[i] = *(const bf16x8*)&base[rr * 64 + sw * 8];
  }
}

template <int NH>
__device__ __forceinline__ void mfma8(const bf16x8* af, const bf16x8* bf,
                                      f32x4 acc[4][4]) {
#pragma unroll
  for (int mt = 0; mt < 4; ++mt)
#pragma unroll
    for (int q = 0; q < 2; ++q)
      acc[mt][NH * 2 + q] = __builtin_amdgcn_mfma_f32_16x16x32_bf16(
          af[mt], bf[NH * 2 + q], acc[mt][NH * 2 + q], 0, 0, 0);
}

#define PHASE_MID()                                       \
  __builtin_amdgcn_s_barrier();                           \
  asm volatile("s_waitcnt lgkmcnt(0)" ::: "memory");      \
  __builtin_amdgcn_sched_barrier(0);                      \
  __builtin_amdgcn_s_setprio(1)

#define PHASE_END()                                       \
  __builtin_amdgcn_s_setprio(0);                          \
  __builtin_amdgcn_sched_barrier(0);                      \
  __builtin_amdgcn_s_barrier()

#define PHASE_END_VM(N)                                   \
  __builtin_amdgcn_s_setprio(0);                          \
  __builtin_amdgcn_sched_barrier(0);                      \
  asm volatile("s_waitcnt vmcnt(" #N ")" ::: "memory");   \
  __builtin_amdgcn_s_barrier()

template <int EPI>
__global__ __launch_bounds__(512, 2) void gemm8p(
    const unsigned short* __restrict__ A, int lda,
    const unsigned short* __restrict__ B, int ldb,
    void* __restrict__ C, int ldc, const int* __restrict__ route, int kLen) {
  __shared__ unsigned short As[2][128 * 64];
  __shared__ unsigned short Bs[2][256 * 64];
  const int lane = threadIdx.x & 63;
  const int wave = threadIdx.x >> 6;      // 0..7
  const int wm = wave >> 2, wn = wave & 3;
  int li = blockIdx.x + gridDim.x * blockIdx.y;
  int bx, by;
  remap_xcd(li, gridDim.x, gridDim.y, bx, by);
  const long rowBase = (long)by * 128;
  const long colBase = (long)bx * 256;
  const int srow = lane >> 3;
  const int scol = ((lane & 7) ^ (srow & 7)) * 8;  // pre-swizzled global src
  const unsigned short* Ag = A + (rowBase + srow) * (long)lda + scol;
  const unsigned short* Bg = B + (colBase + srow) * (long)ldb + scol;
  const int NT = kLen >> 6;

  auto stA = [&](int buf, int t) {  // whole A tile: 16 chunks, 2/wave
#pragma unroll
    for (int c = 0; c < 2; ++c) {
      int chunk = wave * 2 + c;
      __builtin_amdgcn_global_load_lds(
          (const __attribute__((address_space(1))) unsigned int*)(uintptr_t)(
              Ag + (size_t)chunk * 8 * lda + (size_t)t * 64),
          (__attribute__((address_space(3))) unsigned int*)(uintptr_t)(
              &As[buf][chunk * 512]),
          16, 0, 0);
    }
  };
  auto stB = [&](int buf, int t, int h) {  // B half-tile: 16 chunks, 2/wave
#pragma unroll
    for (int c = 0; c < 2; ++c) {
      int chunk = h * 16 + wave * 2 + c;
      __builtin_amdgcn_global_load_lds(
          (const __attribute__((address_space(1))) unsigned int*)(uintptr_t)(
              Bg + (size_t)chunk * 8 * ldb + (size_t)t * 64),
          (__attribute__((address_space(3))) unsigned int*)(uintptr_t)(
              &Bs[buf][chunk * 512]),
          16, 0, 0);
    }
  };

  f32x4 acc[4][4] = {};
  bf16x8 af0[4], af1[4], bf0[4], bf1[4];

  // prologue: tile0 (B halves + A), then the D(-1) stages for tile1
  stB(0, 0, 0);
  stB(0, 0, 1);
  stA(0, 0);
  if (NT > 1) {
    stA(1, 1);
    stB(1, 1, 0);
    asm volatile("s_waitcnt vmcnt(4)" ::: "memory");  // tile0 landed
  } else {
    asm volatile("s_waitcnt vmcnt(0)" ::: "memory");
  }
  __builtin_amdgcn_s_barrier();
  read_frag4(&As[0][0], lane, wm * 64, 0, af0);

  for (int t = 0; t < NT; ++t) {
    const int b = t & 1;
    // ---- phase A: bfr[t,kk0]; stage Bh[t+1][1]
    read_frag4(&Bs[b][0], lane, wn * 64, 0, bf0);
    if (t + 1 < NT) stB(b ^ 1, t + 1, 1);
    PHASE_MID();
    mfma8<0>(af0, bf0, acc);
    PHASE_END();
    // ---- phase B: af[t,kk1]
    read_frag4(&As[b][0], lane, wm * 64, 32, af1);
    PHASE_MID();
    mfma8<1>(af0, bf0, acc);
    PHASE_END();
    // ---- phase C: bfr[t,kk1]; vmcnt(4) -> A[t+1] landed for phase D's read
    read_frag4(&Bs[b][0], lane, wn * 64, 32, bf1);
    PHASE_MID();
    mfma8<0>(af1, bf1, acc);
    PHASE_END_VM(4);
    // ---- phase D: af[t+1,kk0]; stage A[t+2] + Bh[t+2][0];
    //      vmcnt(4) -> Bh[t+1][0,1] landed for next phase A's read
    if (t + 1 < NT) read_frag4(&As[b ^ 1][0], lane, wm * 64, 0, af0);
    if (t + 2 < NT) { stA(b, t + 2); stB(b, t + 2, 0); }
    PHASE_MID();
    mfma8<1>(af1, bf1, acc);
    PHASE_END_VM(4);
  }

  // Epilogue. C/D layout (m89-verified): col = lane&15, row = (lane>>4)*4 + r.
  const int rsub = (lane >> 4) * 4;
  const int csub = lane & 15;
#pragma unroll
  for (int mt = 0; mt < 4; ++mt) {
#pragma unroll
    for (int nt = 0; nt < 4; ++nt) {
      long col = colBase + wn * 64 + nt * 16 + csub;
#pragma unroll
      for (int r = 0; r < 4; ++r) {
        long row = rowBase + wm * 64 + mt * 16 + rsub + r;
        float v = acc[mt][nt][r];
        if (EPI == 0) {
          float s = __fdividef(v, 1.0f + __expf(-v));  // silu
          ((unsigned short*)C)[row * ldc + col] = f2bf(s);
        } else if (EPI == 1) {
          ((float*)C)[row * ldc + col] = v;
        } else {  // EPI == 3: expert-select store into a_sel [TOK][ADP] fp32
          if (route[row] == (int)(col >> 8))
            ((float*)C)[row * ADP + (col & 255)] = v;
        }
      }
    }
  }
}

// ---------------------------------------------------------------------------
// Legacy 128x128x(BK=64) m97-structure GEMM body — retained for the dual
// split-K launch only (small K-slices, needs split-K parallelism).
// ---------------------------------------------------------------------------
__device__ __forceinline__ void stage_tile(const unsigned short* __restrict__ g,
                                           int ldg, unsigned short* lds,
                                           int wave, int lane) {
  int srow = lane >> 3;
  int scol = ((lane & 7) ^ (srow & 7)) * 8;
#pragma unroll
  for (int c = 0; c < 4; ++c) {
    int chunk = wave * 4 + c;
    const unsigned short* gp = g + (size_t)(chunk * 8 + srow) * ldg + scol;
    unsigned short* lp = lds + chunk * 512;
    __builtin_amdgcn_global_load_lds(
        (const __attribute__((address_space(1))) unsigned int*)(uintptr_t)gp,
        (__attribute__((address_space(3))) unsigned int*)(uintptr_t)lp,
        16, 0, 0);
  }
}

__device__ __forceinline__ void gemm_body1(
    int bxr, int byr, int bz,
    const unsigned short* __restrict__ A, int lda,
    const unsigned short* __restrict__ B, int ldb,
    float* __restrict__ C, int ldc, int kLen, long splitStride,
    unsigned short* As, unsigned short* Bs) {
  const int lane = threadIdx.x & 63;
  const int wave = threadIdx.x >> 6;
  const int wm = wave >> 1, wn = wave & 1;
  const long rowBase = (long)byr * 128;
  const long colBase = (long)bxr * 128;
  const int ks = bz * kLen;
  const unsigned short* Ap = A + rowBase * lda + ks;
  const unsigned short* Bp = B + colBase * ldb + ks;
  f32x4 acc[4][4] = {};

  for (int kt = 0; kt < kLen; kt += 64) {
    stage_tile(Ap + kt, lda, As, wave, lane);
    stage_tile(Bp + kt, ldb, Bs, wave, lane);
    __syncthreads();
#pragma unroll
    for (int kk = 0; kk < 64; kk += 32) {
      const int kb = (kk >> 3) + (lane >> 4);
      const int sw = kb ^ (lane & 7);
      bf16x8 af[4], bfr[4];
#pragma unroll
      for (int mt = 0; mt < 4; ++mt) {
        int m = wm * 64 + mt * 16 + (lane & 15);
        af[mt] = *(const bf16x8*)&As[m * 64 + sw * 8];
      }
#pragma unroll
      for (int nt = 0; nt < 4; ++nt) {
        int n = wn * 64 + nt * 16 + (lane & 15);
        bfr[nt] = *(const bf16x8*)&Bs[n * 64 + sw * 8];
      }
#pragma unroll
      for (int mt = 0; mt < 4; ++mt)
#pragma unroll
        for (int nt = 0; nt < 4; ++nt)
          acc[mt][nt] = __builtin_amdgcn_mfma_f32_16x16x32_bf16(
              af[mt], bfr[nt], acc[mt][nt], 0, 0, 0);
    }
    __syncthreads();
  }

  const int rsub = (lane >> 4) * 4;
  const int csub = lane & 15;
#pragma unroll
  for (int mt = 0; mt < 4; ++mt) {
#pragma unroll
    for (int nt = 0; nt < 4; ++nt) {
      long col = colBase + wn * 64 + nt * 16 + csub;
#pragma unroll
      for (int r = 0; r < 4; ++r) {
        long row = rowBase + wm * 64 + mt * 16 + rsub + r;
        (C + splitStride * bz)[row * ldc + col] = acc[mt][nt][r];
      }
    }
  }
}

// ---------------------------------------------------------------------------
// Dual GEMM launch (both split-K fp32): blocks [0,nb0) run grid0, rest grid1.
// Hides the tiny Wcomb split-K GEMM inside the adapt split-K launch.
// ---------------------------------------------------------------------------
__global__ __launch_bounds__(256, 3) void gemm_dual(
    const unsigned short* __restrict__ A0, int lda0,
    const unsigned short* __restrict__ B0, int ldb0,
    float* __restrict__ C0, int ldc0, int kLen0, long ss0, int gx0, int gy0,
    int nb0,
    const unsigned short* __restrict__ A1, int lda1,
    const unsigned short* __restrict__ B1, int ldb1,
    float* __restrict__ C1, int ldc1, int kLen1, long ss1, int gx1, int gy1) {
  __shared__ unsigned short As[128 * 64];
  __shared__ unsigned short Bs[128 * 64];
  int li = blockIdx.x;
  if (li < nb0) {
    int per = gx0 * gy0;
    int z = li / per, rem = li % per;
    int bx, by;
    remap_xcd(rem, gx0, gy0, bx, by);
    gemm_body1(bx, by, z, A0, lda0, B0, ldb0, C0, ldc0, kLen0, ss0, As, Bs);
  } else {
    int wli = li - nb0;
    int per = gx1 * gy1;
    int z = wli / per, rem = wli % per;
    int bx, by;
    remap_xcd(rem, gx1, gy1, bx, by);
    gemm_body1(bx, by, z, A1, lda1, B1, ldb1, C1, ldc1, kLen1, ss1, As, Bs);
  }
}

// ---------------------------------------------------------------------------
// Merged elementwise reductions (block-range dispatch):
//   [0,2048)    : sum 4 split-K fp32 partials of A -> bf16 ab
//   [2048,2304) : sum 8 split-K fp32 partials of Wcomb, x0.1 -> bf16 tail of wob
// ---------------------------------------------------------------------------
__global__ __launch_bounds__(256) void reduce_both(
    const float* __restrict__ P, unsigned short* __restrict__ ab,
    const float* __restrict__ Pw, unsigned short* __restrict__ wob) {
  int b = blockIdx.x;
  if (b < 2048) {
    size_t i = ((size_t)b * 256 + threadIdx.x) * 4;
    const size_t stride = (size_t)TOK * ADP;
    float4 p0 = *(const float4*)(P + i);
    float4 p1 = *(const float4*)(P + stride + i);
    float4 p2 = *(const float4*)(P + 2 * stride + i);
    float4 p3 = *(const float4*)(P + 3 * stride + i);
    ushort4 o;
    o.x = f2bf(p0.x + p1.x + p2.x + p3.x);
    o.y = f2bf(p0.y + p1.y + p2.y + p3.y);
    o.z = f2bf(p0.z + p1.z + p2.z + p3.z);
    o.w = f2bf(p0.w + p1.w + p2.w + p3.w);
    *(ushort4*)(ab + i) = o;
  } else {
    size_t i = ((size_t)(b - 2048) * 256 + threadIdx.x) * 4;  // over 1024*256
    const size_t stride = (size_t)DEMB * ADP;
    float4 s = *(const float4*)(Pw + i);
#pragma unroll
    for (int k = 1; k < 8; ++k) {
      float4 p = *(const float4*)(Pw + k * stride + i);
      s.x += p.x; s.y += p.y; s.z += p.z; s.w += p.w;
    }
    size_t d = i >> 8, a = i & 255;
    ushort4 o;
    o.x = f2bf(0.1f * s.x); o.y = f2bf(0.1f * s.y);
    o.z = f2bf(0.1f * s.z); o.w = f2bf(0.1f * s.w);
    *(ushort4*)(wob + d * KAUG + HID + a) = o;
  }
}

// ---------------------------------------------------------------------------
// LayerNorm over a_sel rows: one WAVE per token (4 tokens / 256-thread block).
// Writes bf16 a_norm into the tail columns [4096..4351] of H_aug (0 for
// inactive tokens); the 0.1 combine scale is folded into Wcomb.
// ---------------------------------------------------------------------------
__global__ __launch_bounds__(256) void ln_kernel(
    const float* __restrict__ asel, const int* __restrict__ route,
    const float* __restrict__ gamma, const float* __restrict__ beta,
    unsigned short* __restrict__ haug) {
  const int lane = threadIdx.x & 63;
  const int t = blockIdx.x * 4 + (threadIdx.x >> 6);
  const int e = route[t];
  float4 v = *(const float4*)(asel + (size_t)t * ADP + lane * 4);
  float s1 = v.x + v.y + v.z + v.w;
  float s2 = v.x * v.x + v.y * v.y + v.z * v.z + v.w * v.w;
#pragma unroll
  for (int off = 32; off > 0; off >>= 1) {
    s1 += __shfl_down(s1, off);
    s2 += __shfl_down(s2, off);
  }
  s1 = __shfl(s1, 0);
  s2 = __shfl(s2, 0);
  float mu = s1 * (1.0f / ADP);
  float var = s2 * (1.0f / ADP) - mu * mu;
  float rstd = rsqrtf(var + 1e-5f);
  ushort4 o;
  if (e >= 0) {
    float4 g = *(const float4*)(gamma + (size_t)e * ADP + lane * 4);
    float4 b = *(const float4*)(beta + (size_t)e * ADP + lane * 4);
    o.x = f2bf((v.x - mu) * rstd * g.x + b.x);
    o.y = f2bf((v.y - mu) * rstd * g.y + b.y);
    o.z = f2bf((v.z - mu) * rstd * g.z + b.z);
    o.w = f2bf((v.w - mu) * rstd * g.w + b.w);
  } else {
    o.x = o.y = o.z = o.w = 0;
  }
  *(ushort4*)(haug + (size_t)t * KAUG + HID + lane * 4) = o;
}

// ---------------------------------------------------------------------------
extern "C" void kernel_launch(void* const* d_in, const int* in_sizes, int n_in,
                              void* d_out, int out_size, void* d_ws, size_t ws_size,
                              hipStream_t stream) {
  const float* x     = (const float*)d_in[0];
  const float* ew    = (const float*)d_in[1];
  const float* W_up  = (const float*)d_in[2];
  const float* W_ad  = (const float*)d_in[3];
  const float* W_ex  = (const float*)d_in[4];
  const float* gam   = (const float*)d_in[5];
  const float* bet   = (const float*)d_in[6];
  const float* W_pr  = (const float*)d_in[7];
  const float* W_out = (const float*)d_in[8];
  float* out = (float*)d_out;

  // workspace layout (~150 MiB total)
  char* ws = (char*)d_ws;
  size_t off = 0;
  auto alloc = [&](size_t n) {
    char* p = ws + off;
    off += (n + 255) & ~(size_t)255;
    return p;
  };
  unsigned short* xb   = (unsigned short*)alloc((size_t)TOK * DEMB * 2);
  unsigned short* wub  = (unsigned short*)alloc((size_t)HID * DEMB * 2);
  unsigned short* wob  = (unsigned short*)alloc((size_t)DEMB * KAUG * 2);  // [Wout | Wcomb]
  unsigned short* wab  = (unsigned short*)alloc((size_t)ADP * HID * 2);
  unsigned short* web  = (unsigned short*)alloc((size_t)NEXP * ADP * ADP * 2);
  unsigned short* wpT  = (unsigned short*)alloc((size_t)ADP * HID * 2);    // Wproj^T bf16
  unsigned short* Haug = (unsigned short*)alloc((size_t)TOK * KAUG * 2);   // [H | anorm]
  float*          P    = (float*)alloc((size_t)4 * TOK * ADP * 4);
  float*          Pw   = (float*)alloc((size_t)8 * DEMB * ADP * 4);
  unsigned short* ab   = (unsigned short*)alloc((size_t)TOK * ADP * 2);
  int*          route  = (int*)alloc((size_t)TOK * 4);
  // a_sel aliases P: P fully consumed by reduce_both before gemm8p<3> writes.
  float* asel = P;

  // 1) bf16 conversion of x + weights + routing + Wproj^T  (one launch)
  convert_all<<<9248, 256, 0, stream>>>(x, W_up, W_out, W_ad, W_ex, ew, W_pr,
                                        xb, wub, wob, wab, web, route, wpT);
  // 2) H = silu(x @ W_up^T) into cols [0,4096) of H_aug  (8-phase, 1024 blks)
  gemm8p<0><<<dim3(HID / 256, TOK / 128, 1), 512, 0, stream>>>(
      xb, DEMB, wub, DEMB, Haug, KAUG, nullptr, DEMB);
  // 3) dual: A = H @ W_adapt^T (split-K=4, 512 blocks)
  //        + Wcomb = W_out @ W_proj (split-K=8, 128 blocks) in one launch
  gemm_dual<<<640, 256, 0, stream>>>(
      Haug, KAUG, wab, HID, P, ADP, HID / 4, (long)TOK * ADP, 2, 64, 512,
      wob, KAUG, wpT, HID, Pw, ADP, HID / 8, (long)DEMB * ADP, 2, 8);
  // 4) merged reductions: a partials -> bf16 ab; Wcomb partials -> wob tail
  reduce_both<<<2304, 256, 0, stream>>>(P, ab, Pw, wob);
  // 5) a_all = a @ W_all^T for all 8 experts; keep winning slice -> a_sel
  gemm8p<3><<<dim3(NEXP * ADP / 256, TOK / 128, 1), 512, 0, stream>>>(
      ab, ADP, web, ADP, asel, ADP, route, ADP);
  // 6) LayerNorm per token -> bf16 into tail cols of H_aug
  ln_kernel<<<TOK / 4, 256, 0, stream>>>(asel, route, gam, bet, Haug);
  // 7) out = H_aug @ [Wout | Wcomb]^T, K=4352  (8-phase, 256 blocks = 1/CU)
  gemm8p<1><<<dim3(DEMB / 256, TOK / 128, 1), 512, 0, stream>>>(
      Haug, KAUG, wob, KAUG, out, DEMB, nullptr, KAUG);
}

// Round 2
// 348.714 us; speedup vs baseline: 1.0304x; 1.0304x over previous
//
#include <hip/hip_runtime.h>
#include <cstdint>

// Problem constants (fixed by reference: B=4, S=2048)
#define TOK  8192   // B*S
#define DEMB 1024   // N_EMBD
#define HID  4096   // HIDDEN
#define ADP  256    // ADAPT
#define NEXP 8
#define KAUG 4352   // HID + ADP (K-augmented out-proj)

typedef __bf16 bf16x8 __attribute__((ext_vector_type(8)));
typedef float  f32x4  __attribute__((ext_vector_type(4)));

__device__ __forceinline__ unsigned short f2bf(float f) {
  // round-to-nearest-even fp32 -> bf16 (matches numpy/jax cast for normal values)
  unsigned int u = __float_as_uint(f);
  u += 0x7fffu + ((u >> 16) & 1u);
  return (unsigned short)(u >> 16);
}
__device__ __forceinline__ float bf2f(unsigned short b) {
  return __uint_as_float(((unsigned int)b) << 16);
}

// ---------------------------------------------------------------------------
// fp32 -> bf16 conversion for x and weights + routing + Wproj transpose, one
// kernel (block-range dispatch). Blocks:
//   [0,8960)    : 2048-elem conversion chunks (x, wup, wout->strided, wadapt, wexp)
//   [8960,8992) : routing (last active expert, -1 if none)
//   [8992,9248) : transpose-convert W_proj [4096,256] fp32 -> wpT [256,4096] bf16
// ---------------------------------------------------------------------------
__global__ __launch_bounds__(256) void convert_all(
    const float* __restrict__ x, const float* __restrict__ wup,
    const float* __restrict__ wout, const float* __restrict__ wadapt,
    const float* __restrict__ wexp, const float* __restrict__ ew,
    const float* __restrict__ wp,
    unsigned short* __restrict__ xb, unsigned short* __restrict__ wub,
    unsigned short* __restrict__ wob, unsigned short* __restrict__ wab,
    unsigned short* __restrict__ web, int* __restrict__ route,
    unsigned short* __restrict__ wpT) {
  __shared__ float tile[64][65];  // only used by transpose blocks
  int b = blockIdx.x;
  if (b >= 8992) {  // Wproj transpose: 64x64 LDS tiles, pad 65 (2-way = free)
    int wli = b - 8992;
    const int h0 = (wli & 63) * 64;  // over 4096
    const int a0 = (wli >> 6) * 64;  // over 256
    const int t = threadIdx.x;
    const int r = t >> 4;            // 0..15
    const int c = (t & 15) * 4;      // 0..60
#pragma unroll
    for (int p = 0; p < 4; ++p) {
      int row = p * 16 + r;
      float4 v = *(const float4*)(wp + (size_t)(h0 + row) * ADP + a0 + c);
      tile[c + 0][row] = v.x;
      tile[c + 1][row] = v.y;
      tile[c + 2][row] = v.z;
      tile[c + 3][row] = v.w;
    }
    __syncthreads();
#pragma unroll
    for (int q = 0; q < 2; ++q) {
      int idx = q * 256 + t;
      int al = idx >> 3;             // a local 0..63
      int hg = (idx & 7) * 8;        // h local 0,8,..,56
      unsigned int w0 = (unsigned int)f2bf(tile[al][hg + 0]) |
                        ((unsigned int)f2bf(tile[al][hg + 1]) << 16);
      unsigned int w1 = (unsigned int)f2bf(tile[al][hg + 2]) |
                        ((unsigned int)f2bf(tile[al][hg + 3]) << 16);
      unsigned int w2 = (unsigned int)f2bf(tile[al][hg + 4]) |
                        ((unsigned int)f2bf(tile[al][hg + 5]) << 16);
      unsigned int w3 = (unsigned int)f2bf(tile[al][hg + 6]) |
                        ((unsigned int)f2bf(tile[al][hg + 7]) << 16);
      *(uint4*)(wpT + (size_t)(a0 + al) * HID + h0 + hg) =
          make_uint4(w0, w1, w2, w3);
    }
    return;
  }
  if (b >= 8960) {  // routing
    int t = (b - 8960) * 256 + threadIdx.x;
    const float* p = ew + (size_t)t * NEXP;
    int r = -1;
#pragma unroll
    for (int e = 0; e < NEXP; ++e)
      if (p[e] > 0.f) r = e;
    route[t] = r;
    return;
  }
  const float* src; unsigned short* dst; int lb; bool strided = false;
  if      (b < 4096) { src = x;      dst = xb;  lb = b; }
  else if (b < 6144) { src = wup;    dst = wub; lb = b - 4096; }
  else if (b < 8192) { src = wout;   dst = wob; lb = b - 6144; strided = true; }
  else if (b < 8704) { src = wadapt; dst = wab; lb = b - 8192; }
  else               { src = wexp;   dst = web; lb = b - 8704; }
  size_t base = (size_t)lb * 2048;
#pragma unroll
  for (int h = 0; h < 2; ++h) {
    size_t off = base + (size_t)h * 1024 + (size_t)threadIdx.x * 4;
    float4 v = *(const float4*)(src + off);
    ushort4 o;
    o.x = f2bf(v.x); o.y = f2bf(v.y); o.z = f2bf(v.z); o.w = f2bf(v.w);
    size_t doff = strided ? (off >> 12) * KAUG + (off & 4095) : off;
    *(ushort4*)(dst + doff) = o;
  }
}

// XCD-aware remap: raw round-robin puts one N-strip per XCD and streams all
// of A through every XCD. Remap gives each XCD a contiguous band of gy/8
// row-tiles with all col-tiles co-resident (requires (gx*gy) % 8 == 0).
__device__ __forceinline__ void remap_xcd(int li, int gx, int gy,
                                          int& bx, int& by) {
  int xcd = li & 7;
  int slot = li >> 3;
  bx = slot % gx;
  by = xcd * (gy >> 3) + slot / gx;
}

#define PHASE_MID()                                       \
  __builtin_amdgcn_s_barrier();                           \
  asm volatile("s_waitcnt lgkmcnt(0)" ::: "memory");      \
  __builtin_amdgcn_sched_barrier(0);                      \
  __builtin_amdgcn_s_setprio(1)

#define PHASE_END()                                       \
  __builtin_amdgcn_s_setprio(0);                          \
  __builtin_amdgcn_sched_barrier(0);                      \
  __builtin_amdgcn_s_barrier()

#define PHASE_END_VM(N)                                   \
  __builtin_amdgcn_s_setprio(0);                          \
  __builtin_amdgcn_sched_barrier(0);                      \
  asm volatile("s_waitcnt vmcnt(" #N ")" ::: "memory");   \
  __builtin_amdgcn_s_barrier()

// ===========================================================================
// gemm256: m201-geometry 256x256x(BK=64) bf16 MFMA GEMM, C = A @ B^T.
// 8 waves (2M x 4N), per-wave 128x64 output (acc[8][4]), 16 MFMA per phase,
// LDS 128 KiB = double-buffered A[256x64] + B[256x64] (XOR source-swizzle,
// bank-conflict-free), staged as HALF-tiles (128 rows = 16 chunks, 2/wave).
//
// Per-wave sub-rows interleave across staging halves:
//   A rows: mhalf*128 + wm*64 + mt*16   B cols: nhalf*128 + wn*32 + nt*16
// so a wave's (mhalf/nhalf) fragments live entirely in staging half mhalf —
// the half-readiness hazard maps 1:1 onto the staged half-tiles.
//
// Per K-tile t (buf b, next nb), 4 phases x 16 MFMA (quadrants of the
// per-wave 128x64 C), reads one phase ahead of use, stages distributed:
//   P0: rd bf1(t) ; stage {Ah0,Bh0}(t+1) ; MFMA Q(m0,n0) ; vmcnt(4)
//   P1: rd af1(t) ; stage {Bh1,Ah1}(t+1) ; MFMA Q(m0,n1) ; vmcnt(6)
//   P2: rd af0(t+1)                      ; MFMA Q(m1,n0) ; vmcnt(4)
//   P3: rd bf0(t+1)                      ; MFMA Q(m1,n1) ; vmcnt(2|0 tail)
// vmcnt derivation (2 loads per half-tile stage, issue order as above):
//   end P0: wait Ah1(t)   [P1(t-1) batch tail]  -> vmcnt(4)
//   end P1: wait Ah0(t+1) [P0(t) batch head]    -> vmcnt(6)
//   end P2: wait Bh0(t+1) [P0(t) batch tail]    -> vmcnt(4)
//   end P3: wait Bh1(t+1) [P1(t) batch head]    -> vmcnt(2)
// Reads land in the phase AFTER the enforcing {vmcnt; barrier} -> all waves'
// stages visible. EPI: 0 = silu->bf16, 1 = fp32, 3 = expert-select fp32.
// ===========================================================================
template <int MB, int NB>
__device__ __forceinline__ void mfmaQ(const bf16x8 af[4][2], const bf16x8 bf[2][2],
                                      f32x4 acc[8][4]) {
#pragma unroll
  for (int mt = 0; mt < 4; ++mt)
#pragma unroll
    for (int nt = 0; nt < 2; ++nt)
#pragma unroll
      for (int kk = 0; kk < 2; ++kk)
        acc[MB + mt][NB + nt] = __builtin_amdgcn_mfma_f32_16x16x32_bf16(
            af[mt][kk], bf[nt][kk], acc[MB + mt][NB + nt], 0, 0, 0);
}

template <int EPI>
__global__ __launch_bounds__(512, 2) void gemm256(
    const unsigned short* __restrict__ A, int lda,
    const unsigned short* __restrict__ B, int ldb,
    void* __restrict__ C, int ldc, const int* __restrict__ route, int kLen) {
  __shared__ unsigned short As[2][256 * 64];
  __shared__ unsigned short Bs[2][256 * 64];
  const int lane = threadIdx.x & 63;
  const int wave = threadIdx.x >> 6;      // 0..7
  const int wm = wave >> 2, wn = wave & 3;
  int li = blockIdx.x + gridDim.x * blockIdx.y;
  int bx, by;
  remap_xcd(li, gridDim.x, gridDim.y, bx, by);
  const long rowBase = (long)by * 256;
  const long colBase = (long)bx * 256;
  const int srow = lane >> 3;
  const int scol = ((lane & 7) ^ (srow & 7)) * 8;  // pre-swizzled global src
  const unsigned short* Ag = A + (rowBase + srow) * (long)lda + scol;
  const unsigned short* Bg = B + (colBase + srow) * (long)ldb + scol;
  const int NT = kLen >> 6;

  auto st2 = [&](unsigned short* lds, const unsigned short* g, long ld, int t,
                 int half) {  // one half-tile (128 rows): 16 chunks, 2/wave
#pragma unroll
    for (int c = 0; c < 2; ++c) {
      int chunk = half * 16 + wave * 2 + c;
      __builtin_amdgcn_global_load_lds(
          (const __attribute__((address_space(1))) unsigned int*)(uintptr_t)(
              g + (size_t)chunk * 8 * ld + (size_t)t * 64),
          (__attribute__((address_space(3))) unsigned int*)(uintptr_t)(
              lds + chunk * 512),
          16, 0, 0);
    }
  };
  auto rdA = [&](const unsigned short* base, int mhalf, bf16x8 dst[4][2]) {
#pragma unroll
    for (int mt = 0; mt < 4; ++mt)
#pragma unroll
      for (int kk = 0; kk < 2; ++kk) {
        int rr = mhalf * 128 + wm * 64 + mt * 16 + (lane & 15);
        int sw = (kk * 4 + (lane >> 4)) ^ (lane & 7);  // rr&7 == lane&7
        dst[mt][kk] = *(const bf16x8*)&base[rr * 64 + sw * 8];
      }
  };
  auto rdB = [&](const unsigned short* base, int nhalf, bf16x8 dst[2][2]) {
#pragma unroll
    for (int nt = 0; nt < 2; ++nt)
#pragma unroll
      for (int kk = 0; kk < 2; ++kk) {
        int rr = nhalf * 128 + wn * 32 + nt * 16 + (lane & 15);
        int sw = (kk * 4 + (lane >> 4)) ^ (lane & 7);
        dst[nt][kk] = *(const bf16x8*)&base[rr * 64 + sw * 8];
      }
  };

  f32x4 acc[8][4] = {};
  bf16x8 afA[4][2], afB[4][2], bfA[2][2], bfB[2][2];

  // prologue: stage all 4 halves of tile 0, drain, pre-read af0/bf0
  st2(As[0], Ag, lda, 0, 0);
  st2(Bs[0], Bg, ldb, 0, 0);
  st2(Bs[0], Bg, ldb, 0, 1);
  st2(As[0], Ag, lda, 0, 1);
  asm volatile("s_waitcnt vmcnt(0)" ::: "memory");
  __builtin_amdgcn_s_barrier();
  rdA(As[0], 0, afA);
  rdB(Bs[0], 0, bfA);

  for (int t = 0; t < NT; ++t) {
    const int b = t & 1;
    unsigned short* Asn = As[b ^ 1];
    unsigned short* Bsn = Bs[b ^ 1];
    // ---- P0
    rdB(Bs[b], 1, bfB);
    if (t + 1 < NT) { st2(Asn, Ag, lda, t + 1, 0); st2(Bsn, Bg, ldb, t + 1, 0); }
    PHASE_MID();
    mfmaQ<0, 0>(afA, bfA, acc);
    PHASE_END_VM(4);
    // ---- P1
    rdA(As[b], 1, afB);
    if (t + 1 < NT) { st2(Bsn, Bg, ldb, t + 1, 1); st2(Asn, Ag, lda, t + 1, 1); }
    PHASE_MID();
    mfmaQ<0, 2>(afA, bfB, acc);
    PHASE_END_VM(6);
    // ---- P2
    if (t + 1 < NT) rdA(Asn, 0, afA);
    PHASE_MID();
    mfmaQ<4, 0>(afB, bfA, acc);
    PHASE_END_VM(4);
    // ---- P3
    if (t + 1 < NT) rdB(Bsn, 0, bfA);
    PHASE_MID();
    mfmaQ<4, 2>(afB, bfB, acc);
    if (t + 2 < NT) { PHASE_END_VM(2); } else { PHASE_END_VM(0); }
  }

  // Epilogue. Frag C/D layout (m89): col=lane&15, row=(lane>>4)*4+r.
  // acc[mt][nt]: row = (mt>>2)*128 + wm*64 + (mt&3)*16, col = (nt>>1)*128 + wn*32 + (nt&1)*16.
  const int rsub = (lane >> 4) * 4;
  const int csub = lane & 15;
#pragma unroll
  for (int mt = 0; mt < 8; ++mt) {
#pragma unroll
    for (int nt = 0; nt < 4; ++nt) {
      long col = colBase + (nt >> 1) * 128 + wn * 32 + (nt & 1) * 16 + csub;
#pragma unroll
      for (int r = 0; r < 4; ++r) {
        long row = rowBase + (mt >> 2) * 128 + wm * 64 + (mt & 3) * 16 + rsub + r;
        float v = acc[mt][nt][r];
        if (EPI == 0) {
          float s = __fdividef(v, 1.0f + __expf(-v));  // silu
          ((unsigned short*)C)[row * ldc + col] = f2bf(s);
        } else if (EPI == 1) {
          ((float*)C)[row * ldc + col] = v;
        } else {  // EPI == 3: expert-select store into a_sel [TOK][ADP] fp32
          if (route[row] == (int)(col >> 8))
            ((float*)C)[row * ADP + (col & 255)] = v;
        }
      }
    }
  }
}

// ===========================================================================
// gemm8p: BM=128/BN=256 8-phase kernel (kept for the N=1024 out-proj where a
// 256-wide N tile would leave half the grid idle). See round-1 notes.
// ===========================================================================
__device__ __forceinline__ void read_frag4(const unsigned short* base, int lane,
                                           int rowoff, int kk, bf16x8* dst) {
#pragma unroll
  for (int i = 0; i < 4; ++i) {
    int rr = rowoff + i * 16 + (lane & 15);
    int sw = ((kk >> 3) + (lane >> 4)) ^ (lane & 7);  // rr&7 == lane&7
    dst[i] = *(const bf16x8*)&base[rr * 64 + sw * 8];
  }
}

template <int NH>
__device__ __forceinline__ void mfma8(const bf16x8* af, const bf16x8* bf,
                                      f32x4 acc[4][4]) {
#pragma unroll
  for (int mt = 0; mt < 4; ++mt)
#pragma unroll
    for (int q = 0; q < 2; ++q)
      acc[mt][NH * 2 + q] = __builtin_amdgcn_mfma_f32_16x16x32_bf16(
          af[mt], bf[NH * 2 + q], acc[mt][NH * 2 + q], 0, 0, 0);
}

template <int EPI>
__global__ __launch_bounds__(512, 2) void gemm8p(
    const unsigned short* __restrict__ A, int lda,
    const unsigned short* __restrict__ B, int ldb,
    void* __restrict__ C, int ldc, const int* __restrict__ route, int kLen) {
  __shared__ unsigned short As[2][128 * 64];
  __shared__ unsigned short Bs[2][256 * 64];
  const int lane = threadIdx.x & 63;
  const int wave = threadIdx.x >> 6;      // 0..7
  const int wm = wave >> 2, wn = wave & 3;
  int li = blockIdx.x + gridDim.x * blockIdx.y;
  int bx, by;
  remap_xcd(li, gridDim.x, gridDim.y, bx, by);
  const long rowBase = (long)by * 128;
  const long colBase = (long)bx * 256;
  const int srow = lane >> 3;
  const int scol = ((lane & 7) ^ (srow & 7)) * 8;  // pre-swizzled global src
  const unsigned short* Ag = A + (rowBase + srow) * (long)lda + scol;
  const unsigned short* Bg = B + (colBase + srow) * (long)ldb + scol;
  const int NT = kLen >> 6;

  auto stA = [&](int buf, int t) {  // whole A tile: 16 chunks, 2/wave
#pragma unroll
    for (int c = 0; c < 2; ++c) {
      int chunk = wave * 2 + c;
      __builtin_amdgcn_global_load_lds(
          (const __attribute__((address_space(1))) unsigned int*)(uintptr_t)(
              Ag + (size_t)chunk * 8 * lda + (size_t)t * 64),
          (__attribute__((address_space(3))) unsigned int*)(uintptr_t)(
              &As[buf][chunk * 512]),
          16, 0, 0);
    }
  };
  auto stB = [&](int buf, int t, int h) {  // B half-tile: 16 chunks, 2/wave
#pragma unroll
    for (int c = 0; c < 2; ++c) {
      int chunk = h * 16 + wave * 2 + c;
      __builtin_amdgcn_global_load_lds(
          (const __attribute__((address_space(1))) unsigned int*)(uintptr_t)(
              Bg + (size_t)chunk * 8 * ldb + (size_t)t * 64),
          (__attribute__((address_space(3))) unsigned int*)(uintptr_t)(
              &Bs[buf][chunk * 512]),
          16, 0, 0);
    }
  };

  f32x4 acc[4][4] = {};
  bf16x8 af0[4], af1[4], bf0[4], bf1[4];

  // prologue: tile0 (B halves + A), then the D(-1) stages for tile1
  stB(0, 0, 0);
  stB(0, 0, 1);
  stA(0, 0);
  if (NT > 1) {
    stA(1, 1);
    stB(1, 1, 0);
    asm volatile("s_waitcnt vmcnt(4)" ::: "memory");  // tile0 landed
  } else {
    asm volatile("s_waitcnt vmcnt(0)" ::: "memory");
  }
  __builtin_amdgcn_s_barrier();
  read_frag4(&As[0][0], lane, wm * 64, 0, af0);

  for (int t = 0; t < NT; ++t) {
    const int b = t & 1;
    // ---- phase A: bfr[t,kk0]; stage Bh[t+1][1]
    read_frag4(&Bs[b][0], lane, wn * 64, 0, bf0);
    if (t + 1 < NT) stB(b ^ 1, t + 1, 1);
    PHASE_MID();
    mfma8<0>(af0, bf0, acc);
    PHASE_END();
    // ---- phase B: af[t,kk1]
    read_frag4(&As[b][0], lane, wm * 64, 32, af1);
    PHASE_MID();
    mfma8<1>(af0, bf0, acc);
    PHASE_END();
    // ---- phase C: bfr[t,kk1]; vmcnt(4) -> A[t+1] landed for phase D's read
    read_frag4(&Bs[b][0], lane, wn * 64, 32, bf1);
    PHASE_MID();
    mfma8<0>(af1, bf1, acc);
    PHASE_END_VM(4);
    // ---- phase D: af[t+1,kk0]; stage A[t+2] + Bh[t+2][0];
    //      vmcnt(4) -> Bh[t+1][0,1] landed for next phase A's read
    if (t + 1 < NT) read_frag4(&As[b ^ 1][0], lane, wm * 64, 0, af0);
    if (t + 2 < NT) { stA(b, t + 2); stB(b, t + 2, 0); }
    PHASE_MID();
    mfma8<1>(af1, bf1, acc);
    PHASE_END_VM(4);
  }

  // Epilogue. C/D layout (m89-verified): col = lane&15, row = (lane>>4)*4 + r.
  const int rsub = (lane >> 4) * 4;
  const int csub = lane & 15;
#pragma unroll
  for (int mt = 0; mt < 4; ++mt) {
#pragma unroll
    for (int nt = 0; nt < 4; ++nt) {
      long col = colBase + wn * 64 + nt * 16 + csub;
#pragma unroll
      for (int r = 0; r < 4; ++r) {
        long row = rowBase + wm * 64 + mt * 16 + rsub + r;
        float v = acc[mt][nt][r];
        if (EPI == 0) {
          float s = __fdividef(v, 1.0f + __expf(-v));  // silu
          ((unsigned short*)C)[row * ldc + col] = f2bf(s);
        } else if (EPI == 1) {
          ((float*)C)[row * ldc + col] = v;
        } else {  // EPI == 3
          if (route[row] == (int)(col >> 8))
            ((float*)C)[row * ADP + (col & 255)] = v;
        }
      }
    }
  }
}

// ---------------------------------------------------------------------------
// Legacy 128x128x(BK=64) m97-structure GEMM body — retained for the dual
// split-K launch only (small K-slices, needs split-K parallelism).
// ---------------------------------------------------------------------------
__device__ __forceinline__ void stage_tile(const unsigned short* __restrict__ g,
                                           int ldg, unsigned short* lds,
                                           int wave, int lane) {
  int srow = lane >> 3;
  int scol = ((lane & 7) ^ (srow & 7)) * 8;
#pragma unroll
  for (int c = 0; c < 4; ++c) {
    int chunk = wave * 4 + c;
    const unsigned short* gp = g + (size_t)(chunk * 8 + srow) * ldg + scol;
    unsigned short* lp = lds + chunk * 512;
    __builtin_amdgcn_global_load_lds(
        (const __attribute__((address_space(1))) unsigned int*)(uintptr_t)gp,
        (__attribute__((address_space(3))) unsigned int*)(uintptr_t)lp,
        16, 0, 0);
  }
}

__device__ __forceinline__ void gemm_body1(
    int bxr, int byr, int bz,
    const unsigned short* __restrict__ A, int lda,
    const unsigned short* __restrict__ B, int ldb,
    float* __restrict__ C, int ldc, int kLen, long splitStride,
    unsigned short* As, unsigned short* Bs) {
  const int lane = threadIdx.x & 63;
  const int wave = threadIdx.x >> 6;
  const int wm = wave >> 1, wn = wave & 1;
  const long rowBase = (long)byr * 128;
  const long colBase = (long)bxr * 128;
  const int ks = bz * kLen;
  const unsigned short* Ap = A + rowBase * lda + ks;
  const unsigned short* Bp = B + colBase * ldb + ks;
  f32x4 acc[4][4] = {};

  for (int kt = 0; kt < kLen; kt += 64) {
    stage_tile(Ap + kt, lda, As, wave, lane);
    stage_tile(Bp + kt, ldb, Bs, wave, lane);
    __syncthreads();
#pragma unroll
    for (int kk = 0; kk < 64; kk += 32) {
      const int kb = (kk >> 3) + (lane >> 4);
      const int sw = kb ^ (lane & 7);
      bf16x8 af[4], bfr[4];
#pragma unroll
      for (int mt = 0; mt < 4; ++mt) {
        int m = wm * 64 + mt * 16 + (lane & 15);
        af[mt] = *(const bf16x8*)&As[m * 64 + sw * 8];
      }
#pragma unroll
      for (int nt = 0; nt < 4; ++nt) {
        int n = wn * 64 + nt * 16 + (lane & 15);
        bfr[nt] = *(const bf16x8*)&Bs[n * 64 + sw * 8];
      }
#pragma unroll
      for (int mt = 0; mt < 4; ++mt)
#pragma unroll
        for (int nt = 0; nt < 4; ++nt)
          acc[mt][nt] = __builtin_amdgcn_mfma_f32_16x16x32_bf16(
              af[mt], bfr[nt], acc[mt][nt], 0, 0, 0);
    }
    __syncthreads();
  }

  const int rsub = (lane >> 4) * 4;
  const int csub = lane & 15;
#pragma unroll
  for (int mt = 0; mt < 4; ++mt) {
#pragma unroll
    for (int nt = 0; nt < 4; ++nt) {
      long col = colBase + wn * 64 + nt * 16 + csub;
#pragma unroll
      for (int r = 0; r < 4; ++r) {
        long row = rowBase + wm * 64 + mt * 16 + rsub + r;
        (C + splitStride * bz)[row * ldc + col] = acc[mt][nt][r];
      }
    }
  }
}

// ---------------------------------------------------------------------------
// Dual GEMM launch (both split-K fp32): blocks [0,nb0) run grid0, rest grid1.
// Hides the tiny Wcomb split-K GEMM inside the adapt split-K launch.
// ---------------------------------------------------------------------------
__global__ __launch_bounds__(256, 3) void gemm_dual(
    const unsigned short* __restrict__ A0, int lda0,
    const unsigned short* __restrict__ B0, int ldb0,
    float* __restrict__ C0, int ldc0, int kLen0, long ss0, int gx0, int gy0,
    int nb0,
    const unsigned short* __restrict__ A1, int lda1,
    const unsigned short* __restrict__ B1, int ldb1,
    float* __restrict__ C1, int ldc1, int kLen1, long ss1, int gx1, int gy1) {
  __shared__ unsigned short As[128 * 64];
  __shared__ unsigned short Bs[128 * 64];
  int li = blockIdx.x;
  if (li < nb0) {
    int per = gx0 * gy0;
    int z = li / per, rem = li % per;
    int bx, by;
    remap_xcd(rem, gx0, gy0, bx, by);
    gemm_body1(bx, by, z, A0, lda0, B0, ldb0, C0, ldc0, kLen0, ss0, As, Bs);
  } else {
    int wli = li - nb0;
    int per = gx1 * gy1;
    int z = wli / per, rem = wli % per;
    int bx, by;
    remap_xcd(rem, gx1, gy1, bx, by);
    gemm_body1(bx, by, z, A1, lda1, B1, ldb1, C1, ldc1, kLen1, ss1, As, Bs);
  }
}

// ---------------------------------------------------------------------------
// Merged elementwise reductions (block-range dispatch):
//   [0,2048)    : sum 4 split-K fp32 partials of A -> bf16 ab
//   [2048,2304) : sum 8 split-K fp32 partials of Wcomb, x0.1 -> bf16 tail of wob
// ---------------------------------------------------------------------------
__global__ __launch_bounds__(256) void reduce_both(
    const float* __restrict__ P, unsigned short* __restrict__ ab,
    const float* __restrict__ Pw, unsigned short* __restrict__ wob) {
  int b = blockIdx.x;
  if (b < 2048) {
    size_t i = ((size_t)b * 256 + threadIdx.x) * 4;
    const size_t stride = (size_t)TOK * ADP;
    float4 p0 = *(const float4*)(P + i);
    float4 p1 = *(const float4*)(P + stride + i);
    float4 p2 = *(const float4*)(P + 2 * stride + i);
    float4 p3 = *(const float4*)(P + 3 * stride + i);
    ushort4 o;
    o.x = f2bf(p0.x + p1.x + p2.x + p3.x);
    o.y = f2bf(p0.y + p1.y + p2.y + p3.y);
    o.z = f2bf(p0.z + p1.z + p2.z + p3.z);
    o.w = f2bf(p0.w + p1.w + p2.w + p3.w);
    *(ushort4*)(ab + i) = o;
  } else {
    size_t i = ((size_t)(b - 2048) * 256 + threadIdx.x) * 4;  // over 1024*256
    const size_t stride = (size_t)DEMB * ADP;
    float4 s = *(const float4*)(Pw + i);
#pragma unroll
    for (int k = 1; k < 8; ++k) {
      float4 p = *(const float4*)(Pw + k * stride + i);
      s.x += p.x; s.y += p.y; s.z += p.z; s.w += p.w;
    }
    size_t d = i >> 8, a = i & 255;
    ushort4 o;
    o.x = f2bf(0.1f * s.x); o.y = f2bf(0.1f * s.y);
    o.z = f2bf(0.1f * s.z); o.w = f2bf(0.1f * s.w);
    *(ushort4*)(wob + d * KAUG + HID + a) = o;
  }
}

// ---------------------------------------------------------------------------
// LayerNorm over a_sel rows: one WAVE per token (4 tokens / 256-thread block).
// Writes bf16 a_norm into the tail columns [4096..4351] of H_aug (0 for
// inactive tokens); the 0.1 combine scale is folded into Wcomb.
// ---------------------------------------------------------------------------
__global__ __launch_bounds__(256) void ln_kernel(
    const float* __restrict__ asel, const int* __restrict__ route,
    const float* __restrict__ gamma, const float* __restrict__ beta,
    unsigned short* __restrict__ haug) {
  const int lane = threadIdx.x & 63;
  const int t = blockIdx.x * 4 + (threadIdx.x >> 6);
  const int e = route[t];
  float4 v = *(const float4*)(asel + (size_t)t * ADP + lane * 4);
  float s1 = v.x + v.y + v.z + v.w;
  float s2 = v.x * v.x + v.y * v.y + v.z * v.z + v.w * v.w;
#pragma unroll
  for (int off = 32; off > 0; off >>= 1) {
    s1 += __shfl_down(s1, off);
    s2 += __shfl_down(s2, off);
  }
  s1 = __shfl(s1, 0);
  s2 = __shfl(s2, 0);
  float mu = s1 * (1.0f / ADP);
  float var = s2 * (1.0f / ADP) - mu * mu;
  float rstd = rsqrtf(var + 1e-5f);
  ushort4 o;
  if (e >= 0) {
    float4 g = *(const float4*)(gamma + (size_t)e * ADP + lane * 4);
    float4 b = *(const float4*)(beta + (size_t)e * ADP + lane * 4);
    o.x = f2bf((v.x - mu) * rstd * g.x + b.x);
    o.y = f2bf((v.y - mu) * rstd * g.y + b.y);
    o.z = f2bf((v.z - mu) * rstd * g.z + b.z);
    o.w = f2bf((v.w - mu) * rstd * g.w + b.w);
  } else {
    o.x = o.y = o.z = o.w = 0;
  }
  *(ushort4*)(haug + (size_t)t * KAUG + HID + lane * 4) = o;
}

// ---------------------------------------------------------------------------
extern "C" void kernel_launch(void* const* d_in, const int* in_sizes, int n_in,
                              void* d_out, int out_size, void* d_ws, size_t ws_size,
                              hipStream_t stream) {
  const float* x     = (const float*)d_in[0];
  const float* ew    = (const float*)d_in[1];
  const float* W_up  = (const float*)d_in[2];
  const float* W_ad  = (const float*)d_in[3];
  const float* W_ex  = (const float*)d_in[4];
  const float* gam   = (const float*)d_in[5];
  const float* bet   = (const float*)d_in[6];
  const float* W_pr  = (const float*)d_in[7];
  const float* W_out = (const float*)d_in[8];
  float* out = (float*)d_out;

  // workspace layout (~150 MiB total)
  char* ws = (char*)d_ws;
  size_t off = 0;
  auto alloc = [&](size_t n) {
    char* p = ws + off;
    off += (n + 255) & ~(size_t)255;
    return p;
  };
  unsigned short* xb   = (unsigned short*)alloc((size_t)TOK * DEMB * 2);
  unsigned short* wub  = (unsigned short*)alloc((size_t)HID * DEMB * 2);
  unsigned short* wob  = (unsigned short*)alloc((size_t)DEMB * KAUG * 2);  // [Wout | Wcomb]
  unsigned short* wab  = (unsigned short*)alloc((size_t)ADP * HID * 2);
  unsigned short* web  = (unsigned short*)alloc((size_t)NEXP * ADP * ADP * 2);
  unsigned short* wpT  = (unsigned short*)alloc((size_t)ADP * HID * 2);    // Wproj^T bf16
  unsigned short* Haug = (unsigned short*)alloc((size_t)TOK * KAUG * 2);   // [H | anorm]
  float*          P    = (float*)alloc((size_t)4 * TOK * ADP * 4);
  float*          Pw   = (float*)alloc((size_t)8 * DEMB * ADP * 4);
  unsigned short* ab   = (unsigned short*)alloc((size_t)TOK * ADP * 2);
  int*          route  = (int*)alloc((size_t)TOK * 4);
  // a_sel aliases P: P fully consumed by reduce_both before gemm256<3> writes.
  float* asel = P;

  // 1) bf16 conversion of x + weights + routing + Wproj^T  (one launch)
  convert_all<<<9248, 256, 0, stream>>>(x, W_up, W_out, W_ad, W_ex, ew, W_pr,
                                        xb, wub, wob, wab, web, route, wpT);
  // 2) H = silu(x @ W_up^T) into cols [0,4096) of H_aug  (256^2 8-phase)
  gemm256<0><<<dim3(HID / 256, TOK / 256, 1), 512, 0, stream>>>(
      xb, DEMB, wub, DEMB, Haug, KAUG, nullptr, DEMB);
  // 3) dual: A = H @ W_adapt^T (split-K=4, 512 blocks)
  //        + Wcomb = W_out @ W_proj (split-K=8, 128 blocks) in one launch
  gemm_dual<<<640, 256, 0, stream>>>(
      Haug, KAUG, wab, HID, P, ADP, HID / 4, (long)TOK * ADP, 2, 64, 512,
      wob, KAUG, wpT, HID, Pw, ADP, HID / 8, (long)DEMB * ADP, 2, 8);
  // 4) merged reductions: a partials -> bf16 ab; Wcomb partials -> wob tail
  reduce_both<<<2304, 256, 0, stream>>>(P, ab, Pw, wob);
  // 5) a_all = a @ W_all^T for all 8 experts; keep winning slice -> a_sel
  gemm256<3><<<dim3(NEXP * ADP / 256, TOK / 256, 1), 512, 0, stream>>>(
      ab, ADP, web, ADP, asel, ADP, route, ADP);
  // 6) LayerNorm per token -> bf16 into tail cols of H_aug
  ln_kernel<<<TOK / 4, 256, 0, stream>>>(asel, route, gam, bet, Haug);
  // 7) out = H_aug @ [Wout | Wcomb]^T, K=4352  (8-phase, 256 blocks = 1/CU)
  gemm8p<1><<<dim3(DEMB / 256, TOK / 128, 1), 512, 0, stream>>>(
      Haug, KAUG, wob, KAUG, out, DEMB, nullptr, KAUG);
}